// Round 1
// baseline (193.615 us; speedup 1.0000x reference)
//
#include <hip/hip_runtime.h>
#include <math.h>

typedef _Float16 f16x8 __attribute__((ext_vector_type(8)));
typedef float f32x4 __attribute__((ext_vector_type(4)));

#define CIN 8
#define HIN 128
#define WIN 128
#define OH 126
#define OW 126
#define COUT 64
#define NB 128
#define NGROUPS 16
#define CPG 4
#define PWN 31
#define XROWS 34   // real taps reach row 28+3+2=33; padded khw>=9 clamped to 0

// workspace layout
// f16 ext plane [b][wy][wx][c] | f32 partials [b][g][tile16][{s,sq}]
#define NPOOL (NB*PWN*PWN*COUT)          // 7,872,512 f16 elements
#define OFF_PART (NPOOL/2)               // float offset
#define NPART (NB*NGROUPS*16*2)

// Conv via MFMA implicit GEMM.
// R11 restructure: 512-thread blocks, 8 waves, each wave owns ONE channel
// half (nt=2, 32 ch) x 16 windows. Rationale: the previous 4-wave/nt=4 shape
// needed ~90 live VGPRs (bf=48, acc=16, ...) but the allocator insisted on 64
// -> remat bloat (~4.5K VALU issue/wave measured vs ~2K static). Halving
// channel work per wave drops live state to ~55-60 regs, so the forced
// 64-VGPR cap (512,8) fits WITHOUT remat. Occupancy geometry becomes exact:
// LDS 28.2KB -> 5 blocks/CU possible, wave cap 32/CU -> 4 blocks/CU of 8
// waves = 100% wave occupancy; 2048 blocks = exactly 2 rounds.
__global__ __launch_bounds__(512, 8)
void conv_mfma_kernel(const float* __restrict__ x,
                      const float* __restrict__ w,
                      const float* __restrict__ bias,
                      const float* __restrict__ gnw,
                      const float* __restrict__ scale,
                      float* __restrict__ ws)
{
  __shared__ __align__(16) _Float16 xs[XROWS*34*8];   // 18,496 B
  __shared__ __align__(16) _Float16 wls[9*64*8];      //  9,216 B
  __shared__ float red[8][8][2];                      //    512 B

  const int tid  = threadIdx.x;
  const int lane = tid & 63, wv = tid >> 6;
  const int h    = wv & 1;          // channel half: ch cb..cb+31
  const int wset = wv >> 1;         // window-row set: wyl = wset*2 + {0,1}
  const int tileIdx = blockIdx.x;   // 0..15
  const int tx = tileIdx & 3, ty = tileIdx >> 2;
  const int b  = blockIdx.y;
  const int ox0 = tx*32, oy0 = ty*32;

  // ---- stage weights [khw 9][n 64][ci 8] ----
  for (int idx = tid; idx < 9*64*8; idx += 512) {
    const int ci = idx & 7, n = (idx >> 3) & 63, khw = idx >> 9;
    wls[idx] = (_Float16)w[(n*CIN + ci)*9 + khw];
  }

  // ---- stage x tile: pack 8 ci -> one b128 write per pixel ----
  const float* xb = x + (size_t)b * CIN*HIN*WIN;
  for (int p = tid; p < XROWS*34; p += 512) {
    const int r = p / 34, c = p - r*34;
    const int iy = oy0 + r, ix = ox0 + c;
    const bool ok = (iy < HIN) && (ix < WIN);
    const int gbase = iy*WIN + ix;
    f16x8 pk;
    #pragma unroll
    for (int ci = 0; ci < 8; ++ci) {
      const float v = ok ? xb[ci*HIN*WIN + gbase] : 0.f;
      pk[ci] = (_Float16)v;
    }
    *(f16x8*)&xs[p*8] = pk;
  }
  __syncthreads();

  const int q = lane >> 4, ln = lane & 15;
  const int cb = h*32;              // this wave's channel base

  // B fragments: chunks c=0,1 from LDS; c=2 is khw=8 for q==0, zero otherwise
  f16x8 bf[2][3];
  #pragma unroll
  for (int nt = 0; nt < 2; ++nt) {
    #pragma unroll
    for (int c = 0; c < 2; ++c)
      bf[nt][c] = *(const f16x8*)&wls[((c*4 + q)*64 + cb + nt*16 + ln)*8];
    if (q == 0)
      bf[nt][2] = *(const f16x8*)&wls[((8)*64 + cb + nt*16 + ln)*8];
    else
      bf[nt][2] = (f16x8){0,0,0,0,0,0,0,0};
  }

  // per-lane A offsets (A lane map: m = lane&15 pixel, k-quad = lane>>4)
  const int dy = ln >> 2, dx = ln & 3;
  int aoff[3];
  #pragma unroll
  for (int c = 0; c < 3; ++c) {
    const int khw = c*4 + q;               // 0..11
    const int ky = khw / 3, kx = khw - 3*(khw/3);
    aoff[c] = (khw < 9) ? ((dy + ky)*34 + (dx + kx))*8 : 0;  // clamp padded taps
  }

  float bias_r[2], sgn[2];
  #pragma unroll
  for (int nt = 0; nt < 2; ++nt) {
    const int c = cb + nt*16 + ln;
    bias_r[nt] = bias[c];
    sgn[nt] = (gnw[c]*scale[c] >= 0.f) ? 1.f : -1.f;  // GN slope sign (inv>0)
  }

  float s[2]  = {0.f,0.f};
  float sq[2] = {0.f,0.f};
  _Float16* wext = (_Float16*)ws;

  // 16 pool windows per wave (2 window-rows x 8 cols), 32 channels each
  #pragma unroll 2
  for (int i = 0; i < 16; ++i) {
    const int wyl = wset*2 + (i >> 3), wxl = i & 7;
    const int base = (wyl*4*34 + wxl*4)*8;

    f32x4 acc[2];
    #pragma unroll
    for (int nt = 0; nt < 2; ++nt) {
      const float bv = bias_r[nt];
      acc[nt] = (f32x4){bv, bv, bv, bv};   // bias as MFMA C operand
    }
    #pragma unroll
    for (int c = 0; c < 3; ++c) {
      const f16x8 a = *(const f16x8*)&xs[base + aoff[c]];
      #pragma unroll
      for (int nt = 0; nt < 2; ++nt)
        acc[nt] = __builtin_amdgcn_mfma_f32_16x16x32_f16(a, bf[nt][c], acc[nt], 0, 0, 0);
    }

    const int wyg = ty*8 + wyl, wxg = tx*8 + wxl;
    if ((wyg < PWN) && (wxg < PWN)) {
      const size_t rowbase = ((size_t)(b*PWN + wyg)*PWN + wxg)*COUT;
      float m4[2];
      #pragma unroll
      for (int nt = 0; nt < 2; ++nt) {
        const float v0 = acc[nt][0], v1 = acc[nt][1];
        const float v2 = acc[nt][2], v3 = acc[nt][3];
        s[nt]  += (v0+v1) + (v2+v3);
        sq[nt] += v0*v0 + v1*v1 + v2*v2 + v3*v3;
        const float sg = sgn[nt];
        float m = fmaxf(fmaxf(sg*v0, sg*v1), fmaxf(sg*v2, sg*v3));
        m = fmaxf(m, __shfl_xor(m, 16, 64));
        m = fmaxf(m, __shfl_xor(m, 32, 64));
        m4[nt] = sg*m;
      }
      // lanes 0..31 store channels cb..cb+31: lane = q*16+ln -> nt = q
      if (q < 2)
        wext[rowbase + cb + lane] = (_Float16)(q ? m4[1] : m4[0]);
    } else {
      // edge windows (wyg==31 or wxg==31): stats only, masked to 126x126
      const bool yv = (wyg*4 + q) < OH;
      #pragma unroll
      for (int nt = 0; nt < 2; ++nt) {
        #pragma unroll
        for (int r = 0; r < 4; ++r) {
          const bool okp = yv && (wxg*4 + r < OW);
          const float v = okp ? acc[nt][r] : 0.f;
          s[nt] += v; sq[nt] += v*v;
        }
      }
    }
  }

  // per-wave stat reduce: quads (xor 16,32) then channels-in-group (xor 1,2)
  #pragma unroll
  for (int nt = 0; nt < 2; ++nt) {
    float a = s[nt], c2 = sq[nt];
    a  += __shfl_xor(a, 16, 64);  a  += __shfl_xor(a, 32, 64);
    a  += __shfl_xor(a, 1, 64);   a  += __shfl_xor(a, 2, 64);
    c2 += __shfl_xor(c2, 16, 64); c2 += __shfl_xor(c2, 32, 64);
    c2 += __shfl_xor(c2, 1, 64);  c2 += __shfl_xor(c2, 2, 64);
    if (lane < 16 && (lane & 3) == 0) {
      red[wv][nt*4 + (ln >> 2)][0] = a;    // g_local = nt*4 + ln>>2 (0..7)
      red[wv][nt*4 + (ln >> 2)][1] = c2;
    }
  }
  __syncthreads();
  if (tid < 32) {
    const int g = tid >> 1, k = tid & 1;       // g = hg*8 + gl
    const int hg = g >> 3, gl = g & 7;         // waves with wv&1==hg hold gl
    const float t = red[hg][gl][k] + red[hg+2][gl][k]
                  + red[hg+4][gl][k] + red[hg+6][gl][k];
    ws[OFF_PART + (((size_t)b*NGROUPS + g)*16 + tileIdx)*2 + k] = t;
  }
}

// Fused tail: one kernel, 2048 independent blocks (b, xb). Each block
// redundantly computes its batch's GN affine from the L2-hot 1KB partials
// (no cross-block sync, no flags), then applies affine+clamp+NCHW-transpose
// for 2 pooled rows.
__global__ __launch_bounds__(256)
void tail_kernel(const float* __restrict__ gnw,
                 const float* __restrict__ gnb,
                 const float* __restrict__ scale,
                 const float* __restrict__ ws,
                 float* __restrict__ out)
{
  __shared__ float stat[NGROUPS*2];   // [g][{sum,sumsq}]
  __shared__ float AB[128];           // A[64] | B[64]
  __shared__ float vout[COUT*PWN];    // [c][wx], stride 31 -> conflict-free

  const int tid = threadIdx.x;
  const int xb  = blockIdx.x;   // 0..15 -> rows 2*xb, 2*xb+1 (skip >=31)
  const int b   = blockIdx.y;

  if (tid < 32) {
    const int g = tid >> 1, k = tid & 1;
    const float* p = ws + OFF_PART + (size_t)(b*NGROUPS + g)*32 + k;
    float a = 0.f;
    #pragma unroll
    for (int t = 0; t < 16; ++t) a += p[t*2];
    stat[g*2 + k] = a;
  }
  __syncthreads();
  if (tid < COUT) {
    const int c = tid, g = c >> 2;
    const float N = (float)(CPG * OH * OW);
    const float mean = stat[g*2] / N;
    const float var  = stat[g*2 + 1] / N - mean*mean;
    const float inv  = rsqrtf(var + 1e-5f);
    const float ag   = inv * gnw[c];
    AB[c]      = ag * scale[c];
    AB[64 + c] = (gnb[c] - mean * ag) * scale[c];
  }
  __syncthreads();

  const _Float16* wext = (const _Float16*)ws;
  #pragma unroll
  for (int r = 0; r < 2; ++r) {
    const int wy = xb*2 + r;
    if (wy >= PWN) break;
    const size_t rb = (size_t)(b*PWN + wy)*PWN*COUT;   // f16 elements

    if (tid < 248) {                       // 248*8 = 1984 ext elems
      const f16x8 e = *(const f16x8*)&wext[rb + tid*8];
      const int wx = tid >> 3, c0 = (tid & 7)*8;
      #pragma unroll
      for (int j = 0; j < 8; ++j) {
        const int c = c0 + j;
        float v = fmaf(AB[c], (float)e[j], AB[64 + c]);
        v = fminf(fmaxf(v, 0.f), 1.f);
        vout[c*PWN + wx] = v;
      }
    }
    __syncthreads();
    for (int e = tid; e < COUT*PWN; e += 256) {
      const int c = e / PWN, wx = e - c*PWN;
      out[(((size_t)b*COUT + c)*PWN + wy)*PWN + wx] = vout[e];
    }
    __syncthreads();
  }
}

extern "C" void kernel_launch(void* const* d_in, const int* in_sizes, int n_in,
                              void* d_out, int out_size, void* d_ws, size_t ws_size,
                              hipStream_t stream)
{
  const float* x     = (const float*)d_in[0];
  const float* cw    = (const float*)d_in[1];
  const float* cb    = (const float*)d_in[2];
  const float* gnw   = (const float*)d_in[3];
  const float* gnb   = (const float*)d_in[4];
  const float* scale = (const float*)d_in[5];
  float* out = (float*)d_out;
  float* ws  = (float*)d_ws;

  dim3 gridA(16, NB, 1);
  conv_mfma_kernel<<<gridA, 512, 0, stream>>>(x, cw, cb, gnw, scale, ws);

  dim3 gridT(16, NB, 1);
  tail_kernel<<<gridT, 256, 0, stream>>>(gnw, gnb, scale, ws, out);
}

// Round 2
// 184.150 us; speedup vs baseline: 1.0514x; 1.0514x over previous
//
#include <hip/hip_runtime.h>
#include <math.h>

typedef _Float16 f16x8 __attribute__((ext_vector_type(8)));
typedef float f32x4 __attribute__((ext_vector_type(4)));

#define CIN 8
#define HIN 128
#define WIN 128
#define OH 126
#define OW 126
#define COUT 64
#define NB 128
#define NGROUPS 16
#define CPG 4
#define PWN 31
#define XROWS 34   // real taps reach row 28+3+2=33; padded khw>=9 clamped to 0

// workspace layout
// f16 ext plane [b][wy][wx][c] | f32 partials [b][g][tile16][{s,sq}]
#define NPOOL (NB*PWN*PWN*COUT)          // 7,872,512 f16 elements
#define OFF_PART (NPOOL/2)               // float offset
#define NPART (NB*NGROUPS*16*2)

// Conv via MFMA implicit GEMM (R0-proven geometry: 256 thr, 4 waves, nt=4).
// R12: pin the register-allocator occupancy target with waves_per_eu(4,4).
// History: R0 (launch_bounds(256,2)) -> allocator chose 64 VGPRs for ~90
// live values (bf=48, acc=16, stats/addr ~25) and remat'd the rest: ~9.2K
// VALU issue-cycles/wave vs ~3K static. R1 (512 thr, nt=2, lb(512,8)) ->
// allocator went to 32 VGPRs, reloading B-frags from LDS every window
// (bank conflicts 2x, VALU bloat 2x, dur worse). Root cause: AMDGPU regalloc
// chases max-achievable-occupancy (from LDS) and treats remat as free;
// launch_bounds only sets the MIN waves/EU. waves_per_eu(4,4) pins the
// target: budget 512/4 = 128 VGPRs -> all live values stay resident.
__global__ __launch_bounds__(256) __attribute__((amdgpu_waves_per_eu(4, 4)))
void conv_mfma_kernel(const float* __restrict__ x,
                      const float* __restrict__ w,
                      const float* __restrict__ bias,
                      const float* __restrict__ gnw,
                      const float* __restrict__ scale,
                      float* __restrict__ ws)
{
  __shared__ __align__(16) _Float16 xs[XROWS*34*8];   // 18,496 B
  __shared__ __align__(16) _Float16 wls[9*64*8];      //  9,216 B
  __shared__ float red[4][16][2];

  const int tid  = threadIdx.x;
  const int lane = tid & 63, wave = tid >> 6;
  const int tileIdx = blockIdx.x;          // 0..15
  const int tx = tileIdx & 3, ty = tileIdx >> 2;
  const int b  = blockIdx.y;
  const int ox0 = tx*32, oy0 = ty*32;

  // ---- stage weights [khw 9][n 64][ci 8] ----
  for (int idx = tid; idx < 9*64*8; idx += 256) {
    const int ci = idx & 7, n = (idx >> 3) & 63, khw = idx >> 9;
    wls[idx] = (_Float16)w[(n*CIN + ci)*9 + khw];
  }

  // ---- stage x tile: pack 8 ci -> one b128 write per pixel ----
  const float* xb = x + (size_t)b * CIN*HIN*WIN;
  for (int p = tid; p < XROWS*34; p += 256) {
    const int r = p / 34, c = p - r*34;
    const int iy = oy0 + r, ix = ox0 + c;
    const bool ok = (iy < HIN) && (ix < WIN);
    const int gbase = iy*WIN + ix;
    f16x8 pk;
    #pragma unroll
    for (int ci = 0; ci < 8; ++ci) {
      const float v = ok ? xb[ci*HIN*WIN + gbase] : 0.f;
      pk[ci] = (_Float16)v;
    }
    *(f16x8*)&xs[p*8] = pk;
  }
  __syncthreads();

  const int q = lane >> 4, ln = lane & 15;

  // B fragments: chunks c=0,1 from LDS; c=2 is khw=8 for q==0, zero otherwise
  f16x8 bf[4][3];
  #pragma unroll
  for (int nt = 0; nt < 4; ++nt) {
    #pragma unroll
    for (int c = 0; c < 2; ++c)
      bf[nt][c] = *(const f16x8*)&wls[((c*4 + q)*64 + nt*16 + ln)*8];
    if (q == 0)
      bf[nt][2] = *(const f16x8*)&wls[((8)*64 + nt*16 + ln)*8];
    else
      bf[nt][2] = (f16x8){0,0,0,0,0,0,0,0};
  }

  // per-lane A offsets (A lane map: m = lane&15 pixel, k-quad = lane>>4)
  const int dy = ln >> 2, dx = ln & 3;
  int aoff[3];
  #pragma unroll
  for (int c = 0; c < 3; ++c) {
    const int khw = c*4 + q;               // 0..11
    const int ky = khw / 3, kx = khw - 3*(khw/3);
    aoff[c] = (khw < 9) ? ((dy + ky)*34 + (dx + kx))*8 : 0;  // clamp padded taps
  }

  float bias_r[4], sgn[4];
  #pragma unroll
  for (int nt = 0; nt < 4; ++nt) {
    const int c = nt*16 + ln;
    bias_r[nt] = bias[c];
    sgn[nt] = (gnw[c]*scale[c] >= 0.f) ? 1.f : -1.f;  // GN slope sign (inv>0)
  }

  float s[4]  = {0.f,0.f,0.f,0.f};
  float sq[4] = {0.f,0.f,0.f,0.f};
  _Float16* wext = (_Float16*)ws;

  // 16 pool windows per wave (2 window-rows x 8 cols)
  #pragma unroll 2
  for (int i = 0; i < 16; ++i) {
    const int wyl = wave*2 + (i >> 3), wxl = i & 7;
    const int base = (wyl*4*34 + wxl*4)*8;

    f32x4 acc[4];
    #pragma unroll
    for (int nt = 0; nt < 4; ++nt) {
      const float bv = bias_r[nt];
      acc[nt] = (f32x4){bv, bv, bv, bv};   // bias as MFMA C operand
    }
    #pragma unroll
    for (int c = 0; c < 3; ++c) {
      const f16x8 a = *(const f16x8*)&xs[base + aoff[c]];
      #pragma unroll
      for (int nt = 0; nt < 4; ++nt)
        acc[nt] = __builtin_amdgcn_mfma_f32_16x16x32_f16(a, bf[nt][c], acc[nt], 0, 0, 0);
    }

    const int wyg = ty*8 + wyl, wxg = tx*8 + wxl;
    if ((wyg < PWN) && (wxg < PWN)) {
      const size_t rowbase = ((size_t)(b*PWN + wyg)*PWN + wxg)*COUT;
      float m4[4];
      #pragma unroll
      for (int nt = 0; nt < 4; ++nt) {
        const float v0 = acc[nt][0], v1 = acc[nt][1];
        const float v2 = acc[nt][2], v3 = acc[nt][3];
        s[nt]  += (v0+v1) + (v2+v3);
        sq[nt] += v0*v0 + v1*v1 + v2*v2 + v3*v3;
        const float sg = sgn[nt];
        float m = fmaxf(fmaxf(sg*v0, sg*v1), fmaxf(sg*v2, sg*v3));
        m = fmaxf(m, __shfl_xor(m, 16, 64));
        m = fmaxf(m, __shfl_xor(m, 32, 64));
        m4[nt] = sg*m;
      }
      // lane L stores channel c=L: pick m4[L>>4] -> one full-wave 128B store
      float mv = m4[0];
      mv = (q == 1) ? m4[1] : mv;
      mv = (q == 2) ? m4[2] : mv;
      mv = (q == 3) ? m4[3] : mv;
      wext[rowbase + lane] = (_Float16)mv;
    } else {
      // edge windows (wyg==31 or wxg==31): stats only, masked to 126x126
      const bool yv = (wyg*4 + q) < OH;
      #pragma unroll
      for (int nt = 0; nt < 4; ++nt) {
        #pragma unroll
        for (int r = 0; r < 4; ++r) {
          const bool okp = yv && (wxg*4 + r < OW);
          const float v = okp ? acc[nt][r] : 0.f;
          s[nt] += v; sq[nt] += v*v;
        }
      }
    }
  }

  // per-wave stat reduce: quads (xor 16,32) then channels-in-group (xor 1,2)
  #pragma unroll
  for (int nt = 0; nt < 4; ++nt) {
    float a = s[nt], c2 = sq[nt];
    a  += __shfl_xor(a, 16, 64);  a  += __shfl_xor(a, 32, 64);
    a  += __shfl_xor(a, 1, 64);   a  += __shfl_xor(a, 2, 64);
    c2 += __shfl_xor(c2, 16, 64); c2 += __shfl_xor(c2, 32, 64);
    c2 += __shfl_xor(c2, 1, 64);  c2 += __shfl_xor(c2, 2, 64);
    if (lane < 16 && (lane & 3) == 0) {
      red[wave][nt*4 + (ln >> 2)][0] = a;
      red[wave][nt*4 + (ln >> 2)][1] = c2;
    }
  }
  __syncthreads();
  if (tid < 32) {
    const int g = tid >> 1, k = tid & 1;
    const float t = red[0][g][k] + red[1][g][k] + red[2][g][k] + red[3][g][k];
    ws[OFF_PART + (((size_t)b*NGROUPS + g)*16 + tileIdx)*2 + k] = t;
  }
}

// Fused tail: one kernel, 2048 independent blocks (b, xb). Each block
// redundantly computes its batch's GN affine from the L2-hot 1KB partials
// (no cross-block sync, no flags), then applies affine+clamp+NCHW-transpose
// for 2 pooled rows.
__global__ __launch_bounds__(256)
void tail_kernel(const float* __restrict__ gnw,
                 const float* __restrict__ gnb,
                 const float* __restrict__ scale,
                 const float* __restrict__ ws,
                 float* __restrict__ out)
{
  __shared__ float stat[NGROUPS*2];   // [g][{sum,sumsq}]
  __shared__ float AB[128];           // A[64] | B[64]
  __shared__ float vout[COUT*PWN];    // [c][wx], stride 31 -> conflict-free

  const int tid = threadIdx.x;
  const int xb  = blockIdx.x;   // 0..15 -> rows 2*xb, 2*xb+1 (skip >=31)
  const int b   = blockIdx.y;

  if (tid < 32) {
    const int g = tid >> 1, k = tid & 1;
    const float* p = ws + OFF_PART + (size_t)(b*NGROUPS + g)*32 + k;
    float a = 0.f;
    #pragma unroll
    for (int t = 0; t < 16; ++t) a += p[t*2];
    stat[g*2 + k] = a;
  }
  __syncthreads();
  if (tid < COUT) {
    const int c = tid, g = c >> 2;
    const float N = (float)(CPG * OH * OW);
    const float mean = stat[g*2] / N;
    const float var  = stat[g*2 + 1] / N - mean*mean;
    const float inv  = rsqrtf(var + 1e-5f);
    const float ag   = inv * gnw[c];
    AB[c]      = ag * scale[c];
    AB[64 + c] = (gnb[c] - mean * ag) * scale[c];
  }
  __syncthreads();

  const _Float16* wext = (const _Float16*)ws;
  #pragma unroll
  for (int r = 0; r < 2; ++r) {
    const int wy = xb*2 + r;
    if (wy >= PWN) break;
    const size_t rb = (size_t)(b*PWN + wy)*PWN*COUT;   // f16 elements

    if (tid < 248) {                       // 248*8 = 1984 ext elems
      const f16x8 e = *(const f16x8*)&wext[rb + tid*8];
      const int wx = tid >> 3, c0 = (tid & 7)*8;
      #pragma unroll
      for (int j = 0; j < 8; ++j) {
        const int c = c0 + j;
        float v = fmaf(AB[c], (float)e[j], AB[64 + c]);
        v = fminf(fmaxf(v, 0.f), 1.f);
        vout[c*PWN + wx] = v;
      }
    }
    __syncthreads();
    for (int e = tid; e < COUT*PWN; e += 256) {
      const int c = e / PWN, wx = e - c*PWN;
      out[(((size_t)b*COUT + c)*PWN + wy)*PWN + wx] = vout[e];
    }
    __syncthreads();
  }
}

extern "C" void kernel_launch(void* const* d_in, const int* in_sizes, int n_in,
                              void* d_out, int out_size, void* d_ws, size_t ws_size,
                              hipStream_t stream)
{
  const float* x     = (const float*)d_in[0];
  const float* cw    = (const float*)d_in[1];
  const float* cb    = (const float*)d_in[2];
  const float* gnw   = (const float*)d_in[3];
  const float* gnb   = (const float*)d_in[4];
  const float* scale = (const float*)d_in[5];
  float* out = (float*)d_out;
  float* ws  = (float*)d_ws;

  dim3 gridA(16, NB, 1);
  conv_mfma_kernel<<<gridA, 256, 0, stream>>>(x, cw, cb, gnw, scale, ws);

  dim3 gridT(16, NB, 1);
  tail_kernel<<<gridT, 256, 0, stream>>>(gnw, gnb, scale, ws, out);
}